// Round 14
// baseline (1164.902 us; speedup 1.0000x reference)
//
#include <hip/hip_runtime.h>

#define SEQ 2048
#define BATCH 512
#define HDIM 128

typedef __bf16 bf16x8 __attribute__((ext_vector_type(8)));
typedef float  f32x4  __attribute__((ext_vector_type(4)));
typedef unsigned int uint32;

// tanh with input pre-scaled by 2*log2(e): tanh(x) = 1 - 2/(2^(CS*x)+1).
__device__ __forceinline__ float tanh_e2(float y) {
    float e;
    asm("v_exp_f32 %0, %1" : "=v"(e) : "v"(y));
    return fmaf(-2.0f, __builtin_amdgcn_rcpf(e + 1.0f), 1.0f);
}

// x + dpp(x); bound_ctrl=true.
template<int CTRL>
__device__ __forceinline__ float dpp_add(float x) {
    return x + __int_as_float(__builtin_amdgcn_update_dpp(
        0, __float_as_int(x), CTRL, 0xf, 0xf, true));
}

__global__ __launch_bounds__(512, 1)
void odenet_scan_kernel(const float* __restrict__ x,
                        const float* __restrict__ W1,
                        const float* __restrict__ b1,
                        const float* __restrict__ W2,
                        const float* __restrict__ b2,
                        const float* __restrict__ W3,
                        const float* __restrict__ b3,
                        float* __restrict__ out)
{
    const int t  = threadIdx.x;
    const int l  = t & 63;           // lane
    const int wv = t >> 6;           // wave 0..7: owns output cols [16wv, 16wv+16)
    const int b0 = 2 * blockIdx.x;   // TWO chains per block, M-packed: b0, b0+1

    constexpr float CS = 2.8853900817779268f;   // 2*log2(e) tanh prefold

    __shared__ float2 xbuf[SEQ];                       // 16 KB: {xA, xB} per step
    // A staging per wave: rows 0..3 = chA-hi, chA-lo, chB-hi, chB-lo.
    // Row stride 144 ushorts = 288 B = 72 banks === 8 (mod 32).
    __shared__ unsigned short hbuf[8][4 * 144];        // [wave][row*144 + k]
    __shared__ __align__(16) float2 ybuf[2][8];        // [parity][wave] = {yA,yB}

    // ---- one-time: preload x for both chains (adjacent in memory).
    #pragma unroll
    for (int i = 0; i < 4; ++i)
        xbuf[i * 512 + t] = *reinterpret_cast<const float2*>(&x[(i * 512 + t) * BATCH + b0]);

    // ---- one-time: B fragments (CS*W2 hi/lo) for this wave's 16 cols.
    bf16x8 Bhi[4], Blo[4];
    const int bc = 16 * wv + (l & 15);        // this lane's B column
    #pragma unroll
    for (int kt = 0; kt < 4; ++kt) {
        union { unsigned short u[8]; bf16x8 v; } fh, fl;
        #pragma unroll
        for (int j = 0; j < 8; ++j) {
            const int k = 32 * kt + 8 * (l >> 4) + j;
            const float v = W2[k * HDIM + bc] * CS;
            const uint32 u = __float_as_uint(v);
            fh.u[j] = (unsigned short)(u >> 16);
            const float hif = __uint_as_float(u & 0xffff0000u);
            fl.u[j] = (unsigned short)(__float_as_uint(v - hif) >> 16);
        }
        Bhi[kt] = fh.v;
        Blo[kt] = fl.v;
    }

    // ---- layer-1 params: this lane computes h cols 2l, 2l+1 (prescaled CS).
    const float2 w1x_ = *reinterpret_cast<const float2*>(&W1[2 * l]);
    const float2 w1s_ = *reinterpret_cast<const float2*>(&W1[HDIM + 2 * l]);
    const float2 b1v_ = *reinterpret_cast<const float2*>(&b1[2 * l]);
    const float2 w1x = make_float2(w1x_.x * CS, w1x_.y * CS);
    const float2 w1s = make_float2(w1s_.x * CS, w1s_.y * CS);
    const float2 b1v = make_float2(b1v_.x * CS, b1v_.y * CS);

    // ---- layer-2/3 params for this lane's C column (same col for both chains).
    const float b2v = b2[bc] * CS;
    const float w3v = W3[2 * bc + 1];
    const float b31 = b3[1];

    // ---- LDS addresses.
    uint32* pW0 = reinterpret_cast<uint32*>(&hbuf[wv][0 * 144 + 2 * l]);  // chA hi
    uint32* pW1 = reinterpret_cast<uint32*>(&hbuf[wv][1 * 144 + 2 * l]);  // chA lo
    uint32* pW2 = reinterpret_cast<uint32*>(&hbuf[wv][2 * 144 + 2 * l]);  // chB hi
    uint32* pW3 = reinterpret_cast<uint32*>(&hbuf[wv][3 * 144 + 2 * l]);  // chB lo
    // A-read dup trick: lane (row l&15) loads h-row (l&3); C rows 4-15 become
    // harmless duplicates of rows 0-3. 2-way bank aliasing max (free).
    const unsigned short* pA = &hbuf[wv][(l & 3) * 144 + 8 * (l >> 4)];

    __syncthreads();

    float sA = 0.0f, sB = 0.0f, s_hold = 0.0f;
    const float2 x0 = xbuf[0];
    float2 p1A = make_float2(fmaf(w1x.x, x0.x, b1v.x), fmaf(w1x.y, x0.x, b1v.y));
    float2 p1B = make_float2(fmaf(w1x.x, x0.y, b1v.x), fmaf(w1x.y, x0.y, b1v.y));

    for (int n = 0; n < SEQ; ++n) {
        const int par = n & 1;

        // ---- layer 1: 2 cols x 2 chains; split bf16 hi/lo; -> LDS rows 0-3.
        const float hA0 = tanh_e2(fmaf(w1s.x, sA, p1A.x));
        const float hA1 = tanh_e2(fmaf(w1s.y, sA, p1A.y));
        const float hB0 = tanh_e2(fmaf(w1s.x, sB, p1B.x));
        const float hB1 = tanh_e2(fmaf(w1s.y, sB, p1B.y));
        const uint32 uA0 = __float_as_uint(hA0), uA1 = __float_as_uint(hA1);
        const uint32 uB0 = __float_as_uint(hB0), uB1 = __float_as_uint(hB1);
        const uint32 hiA = __builtin_amdgcn_perm(uA1, uA0, 0x07060302u);
        const uint32 hiB = __builtin_amdgcn_perm(uB1, uB0, 0x07060302u);
        const float rA0 = hA0 - __uint_as_float(uA0 & 0xffff0000u);
        const float rA1 = hA1 - __uint_as_float(uA1 & 0xffff0000u);
        const float rB0 = hB0 - __uint_as_float(uB0 & 0xffff0000u);
        const float rB1 = hB1 - __uint_as_float(uB1 & 0xffff0000u);
        const uint32 loA = __builtin_amdgcn_perm(
            __float_as_uint(rA1), __float_as_uint(rA0), 0x07060302u);
        const uint32 loB = __builtin_amdgcn_perm(
            __float_as_uint(rB1), __float_as_uint(rB0), 0x07060302u);
        *pW0 = hiA; *pW1 = loA; *pW2 = hiB; *pW3 = loB;
        __builtin_amdgcn_wave_barrier();   // in-wave LDS write -> read order

        // next x pair + next pre1 (broadcast read, off critical path)
        const float2 xn2 = xbuf[(n + 1) & (SEQ - 1)];
        p1A = make_float2(fmaf(w1x.x, xn2.x, b1v.x), fmaf(w1x.y, xn2.x, b1v.y));
        p1B = make_float2(fmaf(w1x.x, xn2.y, b1v.x), fmaf(w1x.y, xn2.y, b1v.y));

        // ---- matvec: 8 MFMA serve BOTH chains (rows: 0=Ahi 1=Alo 2=Bhi 3=Blo).
        f32x4 Ch = {0.0f, 0.0f, 0.0f, 0.0f};
        f32x4 Cl = {0.0f, 0.0f, 0.0f, 0.0f};
        #pragma unroll
        for (int kt = 0; kt < 4; ++kt) {
            const bf16x8 a = __builtin_bit_cast(bf16x8,
                *reinterpret_cast<const uint4*>(pA + 32 * kt));
            Ch = __builtin_amdgcn_mfma_f32_16x16x32_bf16(a, Bhi[kt], Ch, 0, 0, 0);
            Cl = __builtin_amdgcn_mfma_f32_16x16x32_bf16(a, Blo[kt], Cl, 0, 0, 0);
        }
        __builtin_amdgcn_wave_barrier();   // reads precede next iter's writes

        // ---- 3-term combine per chain + tanh + w3 (cols = lanes, 16-wide).
        const float pAv = (Ch[0] + Ch[1]) + (Cl[0] + b2v);   // chain A
        const float pBv = (Ch[2] + Ch[3]) + (Cl[2] + b2v);   // chain B
        float zA = tanh_e2(pAv) * w3v;
        float zB = tanh_e2(pBv) * w3v;

        // ---- reduce over 16 cols: xor1, xor2, xor4, xor8 (within 16 lanes).
        zA = dpp_add<0xB1>(zA);   zB = dpp_add<0xB1>(zB);
        zA = dpp_add<0x4E>(zA);   zB = dpp_add<0x4E>(zB);
        zA = dpp_add<0x141>(zA);  zB = dpp_add<0x141>(zB);
        zA = dpp_add<0x140>(zA);  zB = dpp_add<0x140>(zB);

        if (l == 0) ybuf[par][wv] = make_float2(zA, zB);
        __syncthreads();   // ONE barrier serves both chains

        const float4* yq = reinterpret_cast<const float4*>(&ybuf[par][0]);
        const float4 q0 = yq[0], q1 = yq[1], q2 = yq[2], q3 = yq[3];
        const float dyA = ((q0.x + q0.z) + (q1.x + q1.z))
                        + ((q2.x + q2.z) + (q3.x + q3.z)) + b31;
        const float dyB = ((q0.y + q0.w) + (q1.y + q1.w))
                        + ((q2.y + q2.w) + (q3.y + q3.w)) + b31;
        sA += dyA;
        sB += dyB;

        // ---- out batching: wave0 stores chain A, wave1 chain B.
        if (wv < 2) {
            if (l == (n & 63)) s_hold = wv ? sB : sA;
            if ((n & 63) == 63) out[(n - 63 + l) * BATCH + b0 + wv] = s_hold;
        }
    }
}

extern "C" void kernel_launch(void* const* d_in, const int* in_sizes, int n_in,
                              void* d_out, int out_size, void* d_ws, size_t ws_size,
                              hipStream_t stream) {
    const float* x  = (const float*)d_in[0];
    const float* W1 = (const float*)d_in[1];
    const float* b1 = (const float*)d_in[2];
    const float* W2 = (const float*)d_in[3];
    const float* b2 = (const float*)d_in[4];
    const float* W3 = (const float*)d_in[5];
    const float* b3 = (const float*)d_in[6];
    float* out = (float*)d_out;

    dim3 grid(BATCH / 2);   // two chains per block, M-packed
    dim3 block(512);        // 8 waves, 16 N-cols each -> 2 waves/SIMD
    odenet_scan_kernel<<<grid, block, 0, stream>>>(x, W1, b1, W2, b2, W3, b3, out);
}

// Round 15
// 988.034 us; speedup vs baseline: 1.1790x; 1.1790x over previous
//
#include <hip/hip_runtime.h>

#define SEQ 2048
#define BATCH 512
#define HDIM 128

typedef __bf16 bf16x8 __attribute__((ext_vector_type(8)));
typedef float  f32x4  __attribute__((ext_vector_type(4)));
typedef unsigned int uint32;

// tanh with input pre-scaled by 2*log2(e): tanh(x) = 1 - 2/(2^(CS*x)+1).
__device__ __forceinline__ float tanh_e2(float y) {
    float e;
    asm("v_exp_f32 %0, %1" : "=v"(e) : "v"(y));
    return fmaf(-2.0f, __builtin_amdgcn_rcpf(e + 1.0f), 1.0f);
}

// x + dpp(x); bound_ctrl=true.
template<int CTRL>
__device__ __forceinline__ float dpp_add(float x) {
    return x + __int_as_float(__builtin_amdgcn_update_dpp(
        0, __float_as_int(x), CTRL, 0xf, 0xf, true));
}

__global__ __launch_bounds__(512, 4)   // 4 waves/SIMD -> 2 blocks/CU
void odenet_scan_kernel(const float* __restrict__ x,
                        const float* __restrict__ W1,
                        const float* __restrict__ b1,
                        const float* __restrict__ W2,
                        const float* __restrict__ b2,
                        const float* __restrict__ W3,
                        const float* __restrict__ b3,
                        float* __restrict__ out)
{
    const int t  = threadIdx.x;
    const int l  = t & 63;           // lane
    const int wv = t >> 6;           // wave 0..7: wave wv owns output cols [16wv,16wv+16)
    const int b  = blockIdx.x;       // ONE chain per block; grid=512 -> 2 blocks/CU

    constexpr float CS = 2.8853900817779268f;   // 2*log2(e) tanh prefold

    __shared__ float xbuf[SEQ];                  // 8 KB: all x for this chain
    // Block-shared h staging: row0 = h_hi (bf16), row1 = h_lo.
    // Row stride 144 ushorts = 288 B (R13-proven conflict-free pattern).
    __shared__ unsigned short hbuf[2][144];
    __shared__ __align__(16) float ybuf[8];      // per-wave y partials (no parity needed)

    // ---- one-time: preload x (4 elems/thread).
    #pragma unroll
    for (int i = 0; i < 4; ++i)
        xbuf[i * 512 + t] = x[(i * 512 + t) * BATCH + b];

    // ---- one-time: B fragments (CS*W2 hi/lo) for this wave's 16 cols.
    bf16x8 Bhi[4], Blo[4];
    const int bc = 16 * wv + (l & 15);           // this lane's B/C column
    #pragma unroll
    for (int kt = 0; kt < 4; ++kt) {
        union { unsigned short u[8]; bf16x8 v; } fh, fl;
        #pragma unroll
        for (int j = 0; j < 8; ++j) {
            const int k = 32 * kt + 8 * (l >> 4) + j;
            const float v = W2[k * HDIM + bc] * CS;
            const uint32 u = __float_as_uint(v);
            fh.u[j] = (unsigned short)(u >> 16);
            const float hif = __uint_as_float(u & 0xffff0000u);
            fl.u[j] = (unsigned short)(__float_as_uint(v - hif) >> 16);
        }
        Bhi[kt] = fh.v;
        Blo[kt] = fl.v;
    }

    // ---- layer-2/3 params.
    const float b2v = b2[bc] * CS;
    const float w3v = W3[2 * bc + 1];
    const float b31 = b3[1];

    // ---- layer-1 params: thread t < 128 owns h column c = t (NO redundancy).
    float w1xv = 0.0f, w1sv = 0.0f, b1vv = 0.0f;
    if (t < 128) {
        w1xv = W1[t] * CS;
        w1sv = W1[HDIM + t] * CS;
        b1vv = b1[t] * CS;
    }

    // ---- A-frag read ptr: lane row (l&15): 0 -> hi, 1..15 -> lo (rows 2-15 dup, unused).
    const int rowe = ((l & 15) == 0) ? 0 : 1;
    const unsigned short* pA = &hbuf[rowe][8 * (l >> 4)];

    __syncthreads();   // x preload visible

    float s = 0.0f, s_hold = 0.0f;

    // ---- prologue: h(0) by threads 0-127 (s = 0).
    if (t < 128) {
        const float h = tanh_e2(fmaf(w1xv, xbuf[0], b1vv));
        const uint32 u = __float_as_uint(h);
        hbuf[0][t] = (unsigned short)(u >> 16);
        const float hf = __uint_as_float(u & 0xffff0000u);
        hbuf[1][t] = (unsigned short)(__float_as_uint(h - hf) >> 16);
    }
    __syncthreads();   // B1(0): h(0) visible

    for (int n = 0; n < SEQ; ++n) {
        // hoist next-x fold (off critical path; only threads < 128 use it)
        float pre1 = 0.0f;
        if (t < 128)
            pre1 = fmaf(w1xv, xbuf[(n + 1) & (SEQ - 1)], b1vv);

        // ---- MFMA phase (all 8 waves): 8 MFMA for this wave's 16 cols.
        f32x4 Ch = {0.0f, 0.0f, 0.0f, 0.0f};
        f32x4 Cl = {0.0f, 0.0f, 0.0f, 0.0f};
        #pragma unroll
        for (int kt = 0; kt < 4; ++kt) {
            const bf16x8 a = __builtin_bit_cast(bf16x8,
                *reinterpret_cast<const uint4*>(pA + 32 * kt));
            Ch = __builtin_amdgcn_mfma_f32_16x16x32_bf16(a, Bhi[kt], Ch, 0, 0, 0);
            Cl = __builtin_amdgcn_mfma_f32_16x16x32_bf16(a, Blo[kt], Cl, 0, 0, 0);
        }
        // 3-term combine (rows 0=hi,1=lo live in lanes 0-15) + tanh + w3.
        const float p = (Ch[0] + Ch[1]) + (Cl[0] + b2v);
        float z = tanh_e2(p) * w3v;
        // reduce over 16 cols: xor1, xor2, xor4, xor8.
        z = dpp_add<0xB1>(z);
        z = dpp_add<0x4E>(z);
        z = dpp_add<0x141>(z);
        z = dpp_add<0x140>(z);
        if (l == 0) ybuf[wv] = z;
        __syncthreads();   // B2(n): y partials visible; all h(n) reads drained

        // ---- s phase (waves 0-1 only; waves 2-7 go wait at B1).
        if (t < 128) {
            const float4 y0 = *reinterpret_cast<const float4*>(&ybuf[0]);
            const float4 y1 = *reinterpret_cast<const float4*>(&ybuf[4]);
            s += ((y0.x + y0.y) + (y0.z + y0.w))
               + ((y1.x + y1.y) + (y1.z + y1.w)) + b31;

            // out batching (wave 0): one scatter store per 64 steps.
            if (t < 64) {
                if (l == (n & 63)) s_hold = s;
                if ((n & 63) == 63) out[(n - 63 + l) * BATCH + b] = s_hold;
            }

            // h(n+1): one column per thread, write hi/lo b16.
            const float h = tanh_e2(fmaf(w1sv, s, pre1));
            const uint32 u = __float_as_uint(h);
            hbuf[0][t] = (unsigned short)(u >> 16);
            const float hf = __uint_as_float(u & 0xffff0000u);
            hbuf[1][t] = (unsigned short)(__float_as_uint(h - hf) >> 16);
        }
        __syncthreads();   // B1(n+1): h(n+1) visible; separates y-write(n+1)/y-read(n)
    }
}

extern "C" void kernel_launch(void* const* d_in, const int* in_sizes, int n_in,
                              void* d_out, int out_size, void* d_ws, size_t ws_size,
                              hipStream_t stream) {
    const float* x  = (const float*)d_in[0];
    const float* W1 = (const float*)d_in[1];
    const float* b1 = (const float*)d_in[2];
    const float* W2 = (const float*)d_in[3];
    const float* b2 = (const float*)d_in[4];
    const float* W3 = (const float*)d_in[5];
    const float* b3 = (const float*)d_in[6];
    float* out = (float*)d_out;

    dim3 grid(BATCH);    // one chain per block -> 2 independent blocks/CU
    dim3 block(512);     // 8 waves: 0-1 own s/layer-1; all do MFMA for 16 cols
    odenet_scan_kernel<<<grid, block, 0, stream>>>(x, W1, b1, W2, b2, W3, b3, out);
}